// Round 3
// baseline (930.347 us; speedup 1.0000x reference)
//
#include <hip/hip_runtime.h>
#include <hip/hip_bf16.h>
#include <math.h>

// bucket = 64 consecutive dst nodes. key packs (dlow<<17 | src), valid for n < 131072.
#define BSHIFT 6
#define BNODES 64
#define MAXB 1024  // max buckets supported by single-block scan (n <= 65536)

// ---------------- dtype detection: int64 vs int32 edge_index ----------------
__global__ void k_detect(const void* edges, long long nn, int* flag) {
    const long long* e64 = (const long long*)edges;
    int ok = 1;
    for (int i = 0; i < 8; ++i) {
        long long v = e64[i];
        if (v < 0 || v >= nn) { ok = 0; break; }
    }
    *flag = ok;
}

// ---------------- per-bucket edge counts (LDS hist -> few global atomics) ----------------
__global__ __launch_bounds__(512) void k_buckcount(const void* edges, const int* __restrict__ flag,
                                                   long long E, int nbuckets, int* totals) {
    __shared__ int cnt[MAXB];
    int t = threadIdx.x;
    for (int b = t; b < nbuckets; b += 512) cnt[b] = 0;
    __syncthreads();
    bool f64 = (*flag != 0);
    long long chunk = (E + gridDim.x - 1) / gridDim.x;
    long long e0 = (long long)blockIdx.x * chunk;
    long long e1 = e0 + chunk; if (e1 > E) e1 = E;
    for (long long e = e0 + t; e < e1; e += 512) {
        int d = f64 ? (int)((const long long*)edges)[E + e] : ((const int*)edges)[E + e];
        atomicAdd(&cnt[d >> BSHIFT], 1);
    }
    __syncthreads();
    for (int b = t; b < nbuckets; b += 512)
        if (cnt[b] > 0) atomicAdd(&totals[b], cnt[b]);
}

// ---------------- single-block scan: base = exclusive(totals), cursor = base ----------------
__global__ __launch_bounds__(1024) void k_scan(const int* __restrict__ totals, int nbuckets,
                                               int* base, int* cursor) {
    __shared__ int tmp[MAXB];
    int t = threadIdx.x;
    int v = (t < nbuckets) ? totals[t] : 0;
    tmp[t] = v;
    __syncthreads();
    for (int off = 1; off < MAXB; off <<= 1) {
        int a = (t >= off) ? tmp[t - off] : 0;
        __syncthreads();
        tmp[t] += a;
        __syncthreads();
    }
    if (t < nbuckets) {
        int ex = tmp[t] - v;
        base[t] = ex;
        cursor[t] = ex;
    }
}

// ---------------- bin edges into bucket-major key array ----------------
__global__ __launch_bounds__(512) void k_binscatter(const void* edges, const int* __restrict__ flag,
                                                    long long E, int nbuckets, int* cursor,
                                                    unsigned int* keys) {
    __shared__ int cnt[MAXB];
    __shared__ int base_l[MAXB];
    int t = threadIdx.x;
    for (int b = t; b < nbuckets; b += 512) cnt[b] = 0;
    __syncthreads();
    bool f64 = (*flag != 0);
    long long chunk = (E + gridDim.x - 1) / gridDim.x;
    long long e0 = (long long)blockIdx.x * chunk;
    long long e1 = e0 + chunk; if (e1 > E) e1 = E;
    // pass 1: local histogram
    for (long long e = e0 + t; e < e1; e += 512) {
        int d = f64 ? (int)((const long long*)edges)[E + e] : ((const int*)edges)[E + e];
        atomicAdd(&cnt[d >> BSHIFT], 1);
    }
    __syncthreads();
    // claim contiguous chunks per bucket
    for (int b = t; b < nbuckets; b += 512) {
        int c = cnt[b];
        base_l[b] = (c > 0) ? atomicAdd(&cursor[b], c) : 0;
        cnt[b] = 0;
    }
    __syncthreads();
    // pass 2: place keys
    for (long long e = e0 + t; e < e1; e += 512) {
        int s, d;
        if (f64) {
            const long long* ee = (const long long*)edges;
            s = (int)ee[e]; d = (int)ee[E + e];
        } else {
            const int* ee = (const int*)edges;
            s = ee[e]; d = ee[E + e];
        }
        int b = d >> BSHIFT;
        int pos = base_l[b] + atomicAdd(&cnt[b], 1);
        keys[pos] = (unsigned int)s | ((unsigned int)(d & (BNODES - 1)) << 17);
    }
}

// ---------------- per-bucket degree -> dinv ----------------
__global__ __launch_bounds__(256) void k_deg(const unsigned int* __restrict__ keys,
                                             const int* __restrict__ base,
                                             const int* __restrict__ totals,
                                             float* dinv, int n) {
    __shared__ int cnt[BNODES];
    int t = threadIdx.x;
    if (t < BNODES) cnt[t] = 0;
    __syncthreads();
    int bk = blockIdx.x;
    int st = base[bk], c = totals[bk];
    for (int i = t; i < c; i += 256) atomicAdd(&cnt[keys[st + i] >> 17], 1);
    __syncthreads();
    int node = bk * BNODES + t;
    if (t < BNODES && node < n) dinv[node] = rsqrtf((float)cnt[t] + 1.0f);
}

// ---------------- GEMM1: h1s[n,64] = dinv * (x[n,64] @ W1[64,64]) ----------------
__global__ __launch_bounds__(256) void k_gemm1(const float* __restrict__ x,
                                               const float* __restrict__ W,
                                               const float* __restrict__ dinv,
                                               float* __restrict__ h) {
    __shared__ float Ws[64][64];
    __shared__ float xs[16][64];
    int t = threadIdx.x;
    for (int i = t; i < 64 * 64; i += 256) Ws[i >> 6][i & 63] = W[i];
    long long row0 = (long long)blockIdx.x * 16;
    ((float4*)xs)[t] = ((const float4*)(x + row0 * 64))[t];
    __syncthreads();
    int r = t >> 4, c0 = (t & 15) * 4;
    float4 acc = {0.f, 0.f, 0.f, 0.f};
#pragma unroll
    for (int k = 0; k < 64; ++k) {
        float xv = xs[r][k];
        float4 wv = *((const float4*)&Ws[k][c0]);
        acc.x += xv * wv.x; acc.y += xv * wv.y;
        acc.z += xv * wv.z; acc.w += xv * wv.w;
    }
    float di = dinv[row0 + r];
    acc.x *= di; acc.y *= di; acc.z *= di; acc.w *= di;
    *((float4*)(h + (row0 + r) * 64 + c0)) = acc;
}

// ---------------- GEMM2: h2s[n,16] = dinv * (out1[n,64] @ W2[64,16]) ----------------
__global__ __launch_bounds__(256) void k_gemm2(const float* __restrict__ h,
                                               const float* __restrict__ W,
                                               const float* __restrict__ dinv,
                                               float* __restrict__ h2) {
    __shared__ float Ws[64 * 16];
    __shared__ float xs[16][64];
    int t = threadIdx.x;
    for (int i = t; i < 64 * 16; i += 256) Ws[i] = W[i];
    long long row0 = (long long)blockIdx.x * 16;
    ((float4*)xs)[t] = ((const float4*)(h + row0 * 64))[t];
    __syncthreads();
    int r = t >> 4, c = t & 15;
    float acc = 0.f;
#pragma unroll
    for (int k = 0; k < 64; ++k) acc += xs[r][k] * Ws[k * 16 + c];
    h2[(row0 + r) * 16 + c] = dinv[row0 + r] * acc;
}

// ---------------- bucket aggregation, 64 feats: LDS tile + ds_add ----------------
__global__ __launch_bounds__(256) void k_agg64(const unsigned int* __restrict__ keys,
                                               const int* __restrict__ base,
                                               const int* __restrict__ totals,
                                               const float* __restrict__ hs,
                                               const float* __restrict__ dinv,
                                               const float* __restrict__ b,
                                               float* __restrict__ out, int n) {
    __shared__ float tile[BNODES * 64];
    int t = threadIdx.x;
    int bk = blockIdx.x;
    int node0 = bk * BNODES;
    int nrows = n - node0; if (nrows > BNODES) nrows = BNODES;
    // init tile with self-loop term (rows contiguous = hs rows)
    for (int i = t; i < nrows * 16; i += 256)
        ((float4*)tile)[i] = ((const float4*)(hs + (long long)node0 * 64))[i];
    __syncthreads();
    int wid = t >> 6, lane = t & 63;
    int st = base[bk], c = totals[bk];
    int i = wid;
    // unroll x2 for two outstanding gathers
    for (; i + 4 < c; i += 8) {
        unsigned int k0 = keys[st + i];
        unsigned int k1 = keys[st + i + 4];
        float v0 = hs[(long long)(k0 & 0x1FFFF) * 64 + lane];
        float v1 = hs[(long long)(k1 & 0x1FFFF) * 64 + lane];
        unsafeAtomicAdd(&tile[(k0 >> 17) * 64 + lane], v0);
        unsafeAtomicAdd(&tile[(k1 >> 17) * 64 + lane], v1);
    }
    for (; i < c; i += 4) {
        unsigned int k0 = keys[st + i];
        float v0 = hs[(long long)(k0 & 0x1FFFF) * 64 + lane];
        unsafeAtomicAdd(&tile[(k0 >> 17) * 64 + lane], v0);
    }
    __syncthreads();
    // epilogue: out = relu(dinv*acc + b)
    for (int idx = t; idx < nrows * 64; idx += 256) {
        int r = idx >> 6, f = idx & 63;
        float v = dinv[node0 + r] * tile[idx] + b[f];
        out[(long long)node0 * 64 + idx] = fmaxf(v, 0.f);
    }
}

// ---------------- bucket aggregation, 16 feats + fused log_softmax ----------------
__global__ __launch_bounds__(256) void k_agg16(const unsigned int* __restrict__ keys,
                                               const int* __restrict__ base,
                                               const int* __restrict__ totals,
                                               const float* __restrict__ hs,
                                               const float* __restrict__ dinv,
                                               const float* __restrict__ b,
                                               float* __restrict__ out, int n) {
    __shared__ float tile[BNODES * 16];
    int t = threadIdx.x;
    int bk = blockIdx.x;
    int node0 = bk * BNODES;
    int nrows = n - node0; if (nrows > BNODES) nrows = BNODES;
    for (int i = t; i < nrows * 4; i += 256)
        ((float4*)tile)[i] = ((const float4*)(hs + (long long)node0 * 16))[i];
    __syncthreads();
    int grp = t >> 4, f = t & 15;  // 16 groups of 16 lanes
    int st = base[bk], c = totals[bk];
    int i = grp;
    for (; i + 16 < c; i += 32) {
        unsigned int k0 = keys[st + i];
        unsigned int k1 = keys[st + i + 16];
        float v0 = hs[(long long)(k0 & 0x1FFFF) * 16 + f];
        float v1 = hs[(long long)(k1 & 0x1FFFF) * 16 + f];
        unsafeAtomicAdd(&tile[(k0 >> 17) * 16 + f], v0);
        unsafeAtomicAdd(&tile[(k1 >> 17) * 16 + f], v1);
    }
    for (; i < c; i += 16) {
        unsigned int k0 = keys[st + i];
        float v0 = hs[(long long)(k0 & 0x1FFFF) * 16 + f];
        unsafeAtomicAdd(&tile[(k0 >> 17) * 16 + f], v0);
    }
    __syncthreads();
    for (int r = t >> 4; r < nrows; r += 16) {
        float v = dinv[node0 + r] * tile[r * 16 + f] + b[f];
        float m = v;
#pragma unroll
        for (int o = 8; o >= 1; o >>= 1) m = fmaxf(m, __shfl_xor(m, o, 16));
        float ex = __expf(v - m);
#pragma unroll
        for (int o = 8; o >= 1; o >>= 1) ex += __shfl_xor(ex, o, 16);
        out[(long long)(node0 + r) * 16 + f] = (v - m) - __logf(ex);
    }
}

extern "C" void kernel_launch(void* const* d_in, const int* in_sizes, int n_in,
                              void* d_out, int out_size, void* d_ws, size_t ws_size,
                              hipStream_t stream) {
    const float* x  = (const float*)d_in[0];
    const void*  ei = d_in[1];
    const float* W1 = (const float*)d_in[2];
    const float* b1 = (const float*)d_in[3];
    const float* W2 = (const float*)d_in[4];
    const float* b2 = (const float*)d_in[5];

    long long dh  = in_sizes[3];                 // 64
    long long din = in_sizes[2] / dh;            // 64
    long long n   = in_sizes[0] / din;           // 50000
    long long E   = (long long)in_sizes[1] / 2;  // 1.6M
    int nbuckets  = (int)((n + BNODES - 1) >> BSHIFT);  // 782

    char* ws = (char*)d_ws;
    auto alloc = [&](size_t bytes) { void* p = ws; ws += (bytes + 255) & ~255ULL; return p; };
    int*   flag   = (int*)alloc(4);
    int*   totals = (int*)alloc(nbuckets * 4);
    int*   base   = (int*)alloc(nbuckets * 4);
    int*   cursor = (int*)alloc(nbuckets * 4);
    float* dinv   = (float*)alloc(n * 4);
    unsigned int* keys = (unsigned int*)alloc(E * 4);
    float* h1s    = (float*)alloc(n * 64 * 4);
    float* out1   = (float*)alloc(n * 64 * 4);
    float* h2s    = h1s;  // h1s dead after k_agg64

    float* out = (float*)d_out;

    hipMemsetAsync(totals, 0, (size_t)nbuckets * 4, stream);

    k_detect<<<1, 1, 0, stream>>>(ei, n, flag);
    k_buckcount<<<128, 512, 0, stream>>>(ei, flag, E, nbuckets, totals);
    k_scan<<<1, 1024, 0, stream>>>(totals, nbuckets, base, cursor);
    k_binscatter<<<128, 512, 0, stream>>>(ei, flag, E, nbuckets, cursor, keys);
    k_deg<<<nbuckets, 256, 0, stream>>>(keys, base, totals, dinv, (int)n);

    // layer 1
    k_gemm1<<<(int)(n / 16), 256, 0, stream>>>(x, W1, dinv, h1s);
    k_agg64<<<nbuckets, 256, 0, stream>>>(keys, base, totals, h1s, dinv, b1, out1, (int)n);

    // layer 2
    k_gemm2<<<(int)(n / 16), 256, 0, stream>>>(out1, W2, dinv, h2s);
    k_agg16<<<nbuckets, 256, 0, stream>>>(keys, base, totals, h2s, dinv, b2, out, (int)n);
}

// Round 4
// 930.025 us; speedup vs baseline: 1.0003x; 1.0003x over previous
//
#include <hip/hip_runtime.h>
#include <hip/hip_bf16.h>
#include <math.h>

// bucket = 64 consecutive dst nodes. key packs (dlow<<17 | src), valid for n < 131072.
#define BSHIFT 6
#define BNODES 64
#define MAXB 1024  // max buckets supported by single-block scan (n <= 65536)

// ---------------- dtype detection: int64 vs int32 edge_index ----------------
__global__ void k_detect(const void* edges, long long nn, int* flag) {
    const long long* e64 = (const long long*)edges;
    int ok = 1;
    for (int i = 0; i < 8; ++i) {
        long long v = e64[i];
        if (v < 0 || v >= nn) { ok = 0; break; }
    }
    *flag = ok;
}

// ---------------- per-bucket edge counts (LDS hist -> few global atomics) ----------------
__global__ __launch_bounds__(512) void k_buckcount(const void* edges, const int* __restrict__ flag,
                                                   long long E, int nbuckets, int* totals) {
    __shared__ int cnt[MAXB];
    int t = threadIdx.x;
    for (int b = t; b < nbuckets; b += 512) cnt[b] = 0;
    __syncthreads();
    bool f64 = (*flag != 0);
    long long chunk = (E + gridDim.x - 1) / gridDim.x;
    long long e0 = (long long)blockIdx.x * chunk;
    long long e1 = e0 + chunk; if (e1 > E) e1 = E;
    for (long long e = e0 + t; e < e1; e += 512) {
        int d = f64 ? (int)((const long long*)edges)[E + e] : ((const int*)edges)[E + e];
        atomicAdd(&cnt[d >> BSHIFT], 1);
    }
    __syncthreads();
    for (int b = t; b < nbuckets; b += 512)
        if (cnt[b] > 0) atomicAdd(&totals[b], cnt[b]);
}

// ---------------- single-block scan: base = exclusive(totals), cursor = base ----------------
__global__ __launch_bounds__(1024) void k_scan(const int* __restrict__ totals, int nbuckets,
                                               int* base, int* cursor) {
    __shared__ int tmp[MAXB];
    int t = threadIdx.x;
    int v = (t < nbuckets) ? totals[t] : 0;
    tmp[t] = v;
    __syncthreads();
    for (int off = 1; off < MAXB; off <<= 1) {
        int a = (t >= off) ? tmp[t - off] : 0;
        __syncthreads();
        tmp[t] += a;
        __syncthreads();
    }
    if (t < nbuckets) {
        int ex = tmp[t] - v;
        base[t] = ex;
        cursor[t] = ex;
    }
}

// ---------------- bin edges into bucket-major key array ----------------
__global__ __launch_bounds__(512) void k_binscatter(const void* edges, const int* __restrict__ flag,
                                                    long long E, int nbuckets, int* cursor,
                                                    unsigned int* keys) {
    __shared__ int cnt[MAXB];
    __shared__ int base_l[MAXB];
    int t = threadIdx.x;
    for (int b = t; b < nbuckets; b += 512) cnt[b] = 0;
    __syncthreads();
    bool f64 = (*flag != 0);
    long long chunk = (E + gridDim.x - 1) / gridDim.x;
    long long e0 = (long long)blockIdx.x * chunk;
    long long e1 = e0 + chunk; if (e1 > E) e1 = E;
    // pass 1: local histogram
    for (long long e = e0 + t; e < e1; e += 512) {
        int d = f64 ? (int)((const long long*)edges)[E + e] : ((const int*)edges)[E + e];
        atomicAdd(&cnt[d >> BSHIFT], 1);
    }
    __syncthreads();
    // claim contiguous chunks per bucket
    for (int b = t; b < nbuckets; b += 512) {
        int c = cnt[b];
        base_l[b] = (c > 0) ? atomicAdd(&cursor[b], c) : 0;
        cnt[b] = 0;
    }
    __syncthreads();
    // pass 2: place keys
    for (long long e = e0 + t; e < e1; e += 512) {
        int s, d;
        if (f64) {
            const long long* ee = (const long long*)edges;
            s = (int)ee[e]; d = (int)ee[E + e];
        } else {
            const int* ee = (const int*)edges;
            s = ee[e]; d = ee[E + e];
        }
        int b = d >> BSHIFT;
        int pos = base_l[b] + atomicAdd(&cnt[b], 1);
        keys[pos] = (unsigned int)s | ((unsigned int)(d & (BNODES - 1)) << 17);
    }
}

// ---------------- per-bucket degree -> dinv ----------------
__global__ __launch_bounds__(256) void k_deg(const unsigned int* __restrict__ keys,
                                             const int* __restrict__ base,
                                             const int* __restrict__ totals,
                                             float* dinv, int n) {
    __shared__ int cnt[BNODES];
    int t = threadIdx.x;
    if (t < BNODES) cnt[t] = 0;
    __syncthreads();
    int bk = blockIdx.x;
    int st = base[bk], c = totals[bk];
    for (int i = t; i < c; i += 256) atomicAdd(&cnt[keys[st + i] >> 17], 1);
    __syncthreads();
    int node = bk * BNODES + t;
    if (t < BNODES && node < n) dinv[node] = rsqrtf((float)cnt[t] + 1.0f);
}

// ---------------- GEMM1: h1s[n,64] = dinv * (x[n,64] @ W1[64,64]) ----------------
__global__ __launch_bounds__(256) void k_gemm1(const float* __restrict__ x,
                                               const float* __restrict__ W,
                                               const float* __restrict__ dinv,
                                               float* __restrict__ h) {
    __shared__ float Ws[64][64];
    __shared__ float xs[16][64];
    int t = threadIdx.x;
    for (int i = t; i < 64 * 64; i += 256) Ws[i >> 6][i & 63] = W[i];
    long long row0 = (long long)blockIdx.x * 16;
    ((float4*)xs)[t] = ((const float4*)(x + row0 * 64))[t];
    __syncthreads();
    int r = t >> 4, c0 = (t & 15) * 4;
    float4 acc = {0.f, 0.f, 0.f, 0.f};
#pragma unroll
    for (int k = 0; k < 64; ++k) {
        float xv = xs[r][k];
        float4 wv = *((const float4*)&Ws[k][c0]);
        acc.x += xv * wv.x; acc.y += xv * wv.y;
        acc.z += xv * wv.z; acc.w += xv * wv.w;
    }
    float di = dinv[row0 + r];
    acc.x *= di; acc.y *= di; acc.z *= di; acc.w *= di;
    *((float4*)(h + (row0 + r) * 64 + c0)) = acc;
}

// ---------------- GEMM2: h2s[n,16] = dinv * (out1[n,64] @ W2[64,16]) ----------------
__global__ __launch_bounds__(256) void k_gemm2(const float* __restrict__ h,
                                               const float* __restrict__ W,
                                               const float* __restrict__ dinv,
                                               float* __restrict__ h2) {
    __shared__ float Ws[64 * 16];
    __shared__ float xs[16][64];
    int t = threadIdx.x;
    for (int i = t; i < 64 * 16; i += 256) Ws[i] = W[i];
    long long row0 = (long long)blockIdx.x * 16;
    ((float4*)xs)[t] = ((const float4*)(h + row0 * 64))[t];
    __syncthreads();
    int r = t >> 4, c = t & 15;
    float acc = 0.f;
#pragma unroll
    for (int k = 0; k < 64; ++k) acc += xs[r][k] * Ws[k * 16 + c];
    h2[(row0 + r) * 16 + c] = dinv[row0 + r] * acc;
}

// ---------------- bucket aggregation, 64 feats: LDS tile + ds_add ----------------
__global__ __launch_bounds__(256) void k_agg64(const unsigned int* __restrict__ keys,
                                               const int* __restrict__ base,
                                               const int* __restrict__ totals,
                                               const float* __restrict__ hs,
                                               const float* __restrict__ dinv,
                                               const float* __restrict__ b,
                                               float* __restrict__ out, int n) {
    __shared__ float tile[BNODES * 64];
    int t = threadIdx.x;
    int bk = blockIdx.x;
    int node0 = bk * BNODES;
    int nrows = n - node0; if (nrows > BNODES) nrows = BNODES;
    // init tile with self-loop term (rows contiguous = hs rows)
    for (int i = t; i < nrows * 16; i += 256)
        ((float4*)tile)[i] = ((const float4*)(hs + (long long)node0 * 64))[i];
    __syncthreads();
    int wid = t >> 6, lane = t & 63;
    int st = base[bk], c = totals[bk];
    int i = wid;
    // unroll x2 for two outstanding gathers
    for (; i + 4 < c; i += 8) {
        unsigned int k0 = keys[st + i];
        unsigned int k1 = keys[st + i + 4];
        float v0 = hs[(long long)(k0 & 0x1FFFF) * 64 + lane];
        float v1 = hs[(long long)(k1 & 0x1FFFF) * 64 + lane];
        unsafeAtomicAdd(&tile[(k0 >> 17) * 64 + lane], v0);
        unsafeAtomicAdd(&tile[(k1 >> 17) * 64 + lane], v1);
    }
    for (; i < c; i += 4) {
        unsigned int k0 = keys[st + i];
        float v0 = hs[(long long)(k0 & 0x1FFFF) * 64 + lane];
        unsafeAtomicAdd(&tile[(k0 >> 17) * 64 + lane], v0);
    }
    __syncthreads();
    // epilogue: out = relu(dinv*acc + b)
    for (int idx = t; idx < nrows * 64; idx += 256) {
        int r = idx >> 6, f = idx & 63;
        float v = dinv[node0 + r] * tile[idx] + b[f];
        out[(long long)node0 * 64 + idx] = fmaxf(v, 0.f);
    }
}

// ---------------- bucket aggregation, 16 feats + fused log_softmax ----------------
__global__ __launch_bounds__(256) void k_agg16(const unsigned int* __restrict__ keys,
                                               const int* __restrict__ base,
                                               const int* __restrict__ totals,
                                               const float* __restrict__ hs,
                                               const float* __restrict__ dinv,
                                               const float* __restrict__ b,
                                               float* __restrict__ out, int n) {
    __shared__ float tile[BNODES * 16];
    int t = threadIdx.x;
    int bk = blockIdx.x;
    int node0 = bk * BNODES;
    int nrows = n - node0; if (nrows > BNODES) nrows = BNODES;
    for (int i = t; i < nrows * 4; i += 256)
        ((float4*)tile)[i] = ((const float4*)(hs + (long long)node0 * 16))[i];
    __syncthreads();
    int grp = t >> 4, f = t & 15;  // 16 groups of 16 lanes
    int st = base[bk], c = totals[bk];
    int i = grp;
    for (; i + 16 < c; i += 32) {
        unsigned int k0 = keys[st + i];
        unsigned int k1 = keys[st + i + 16];
        float v0 = hs[(long long)(k0 & 0x1FFFF) * 16 + f];
        float v1 = hs[(long long)(k1 & 0x1FFFF) * 16 + f];
        unsafeAtomicAdd(&tile[(k0 >> 17) * 16 + f], v0);
        unsafeAtomicAdd(&tile[(k1 >> 17) * 16 + f], v1);
    }
    for (; i < c; i += 16) {
        unsigned int k0 = keys[st + i];
        float v0 = hs[(long long)(k0 & 0x1FFFF) * 16 + f];
        unsafeAtomicAdd(&tile[(k0 >> 17) * 16 + f], v0);
    }
    __syncthreads();
    for (int r = t >> 4; r < nrows; r += 16) {
        float v = dinv[node0 + r] * tile[r * 16 + f] + b[f];
        float m = v;
#pragma unroll
        for (int o = 8; o >= 1; o >>= 1) m = fmaxf(m, __shfl_xor(m, o, 16));
        float ex = __expf(v - m);
#pragma unroll
        for (int o = 8; o >= 1; o >>= 1) ex += __shfl_xor(ex, o, 16);
        out[(long long)(node0 + r) * 16 + f] = (v - m) - __logf(ex);
    }
}

extern "C" void kernel_launch(void* const* d_in, const int* in_sizes, int n_in,
                              void* d_out, int out_size, void* d_ws, size_t ws_size,
                              hipStream_t stream) {
    const float* x  = (const float*)d_in[0];
    const void*  ei = d_in[1];
    const float* W1 = (const float*)d_in[2];
    const float* b1 = (const float*)d_in[3];
    const float* W2 = (const float*)d_in[4];
    const float* b2 = (const float*)d_in[5];

    long long dh  = in_sizes[3];                 // 64
    long long din = in_sizes[2] / dh;            // 64
    long long n   = in_sizes[0] / din;           // 50000
    long long E   = (long long)in_sizes[1] / 2;  // 1.6M
    int nbuckets  = (int)((n + BNODES - 1) >> BSHIFT);  // 782

    char* ws = (char*)d_ws;
    auto alloc = [&](size_t bytes) { void* p = ws; ws += (bytes + 255) & ~255ULL; return p; };
    int*   flag   = (int*)alloc(4);
    int*   totals = (int*)alloc(nbuckets * 4);
    int*   base   = (int*)alloc(nbuckets * 4);
    int*   cursor = (int*)alloc(nbuckets * 4);
    float* dinv   = (float*)alloc(n * 4);
    unsigned int* keys = (unsigned int*)alloc(E * 4);
    float* h1s    = (float*)alloc(n * 64 * 4);
    float* out1   = (float*)alloc(n * 64 * 4);
    float* h2s    = h1s;  // h1s dead after k_agg64

    float* out = (float*)d_out;

    hipMemsetAsync(totals, 0, (size_t)nbuckets * 4, stream);

    k_detect<<<1, 1, 0, stream>>>(ei, n, flag);
    k_buckcount<<<128, 512, 0, stream>>>(ei, flag, E, nbuckets, totals);
    k_scan<<<1, 1024, 0, stream>>>(totals, nbuckets, base, cursor);
    k_binscatter<<<128, 512, 0, stream>>>(ei, flag, E, nbuckets, cursor, keys);
    k_deg<<<nbuckets, 256, 0, stream>>>(keys, base, totals, dinv, (int)n);

    // layer 1
    k_gemm1<<<(int)(n / 16), 256, 0, stream>>>(x, W1, dinv, h1s);
    k_agg64<<<nbuckets, 256, 0, stream>>>(keys, base, totals, h1s, dinv, b1, out1, (int)n);

    // layer 2
    k_gemm2<<<(int)(n / 16), 256, 0, stream>>>(out1, W2, dinv, h2s);
    k_agg16<<<nbuckets, 256, 0, stream>>>(keys, base, totals, h2s, dinv, b2, out, (int)n);
}